// Round 9
// baseline (379.013 us; speedup 1.0000x reference)
//
#include <hip/hip_runtime.h>
#include <math.h>

#define TPB 256

// ---- LDS layout (float offsets), lifetime-overlaid. Weights in GLOBAL/L2. ----
// x   [0,784)      flat [28][28]
// c1  [784,1840)   conv7 out [8][11][12] (even stride for b64 reads)
// y   [784,3384)   dyn out [10][13][20] (16B rows for b128 reads; over c1)
// f   [3384,3474) h [3474,3506) k [3506,3546)   (dead before conv2)
// P2  [3384,5984)  conv2 partials [2][20][65] (over f/h/k after death)
// p3  [0,320) pf [320,570) a1 [570,620) z [620,630)  (x dead after dyn)
#define OX    0
#define OC1   784
#define OY    784
#define OF    3384
#define OH    3474
#define OK2   3506
#define OP2   3384
#define OP3   0
#define OPF   320
#define OA1   570
#define OZ    620
#define SM_TOT 5984   // 23936 B -> 6 blocks/CU

// NOTE: no min-waves launch bound (R3: forced low VGPR -> scratch spill).
// R8 lesson: VGPR must stay <=64 or wave cap halves (84 VGPR -> occupancy
// 60->32%, dur 232->280). This round: R7 structure + b64/b128 reads with
// UNCHANGED live arrays (row[18]/cur[6]/row[12]) so register count holds.
__global__ __launch_bounds__(TPB) void fused_forward(
    const float* __restrict__ x,
    const float* __restrict__ kf_w1, const float* __restrict__ kf_b1,
    const float* __restrict__ kf_w2, const float* __restrict__ kf_b2,
    const float* __restrict__ kf_fc1_w, const float* __restrict__ kf_fc1_b,
    const float* __restrict__ kf_fc2_w, const float* __restrict__ kf_fc2_b,
    const float* __restrict__ conv2_w, const float* __restrict__ conv2_b,
    const float* __restrict__ fc1_w, const float* __restrict__ fc1_b,
    const float* __restrict__ fc2_w, const float* __restrict__ fc2_b,
    float* __restrict__ out)
{
    __shared__ float sm[SM_TOT];
    const int tid = threadIdx.x;
    const int n = blockIdx.x;

    // ---- stage 0: stage x into LDS (float4 flat copy) ----
    {
        const float4* xg = (const float4*)(x + (long long)n * 784);
        float4* d = (float4*)&sm[OX];
        for (int i = tid; i < 196; i += TPB) d[i] = xg[i];
    }
    __syncthreads();

    // ---- conv7 (28->22) + pool (->11) + relu ----
    // oc = tid&7 broadcast; col halves cc0 in {0,12} (even -> 9x b64 row reads;
    // start banks {0,4,8,12,16,20,24,28} disjoint). h0 -> px 0..5, h1 -> px 6..10.
    // h1 reads row[16..17] as harmless garbage (feeds only discarded cc 10,11).
    if (tid < 176) {
        int oc = tid & 7;
        int r  = tid >> 3;
        int py = r >> 1;
        int h  = r & 1;
        int cc0 = 12 * h;
        float c[2][12];
        #pragma unroll
        for (int r2 = 0; r2 < 2; ++r2)
            #pragma unroll
            for (int i = 0; i < 12; ++i) c[r2][i] = 0.f;
        float wc[7], wp[7];
        const float* wg = kf_w1 + oc * 49;
        #pragma unroll
        for (int i = 0; i < 7; ++i) wc[i] = wg[i];
        #pragma unroll
        for (int t = 0; t < 8; ++t) {
            const float2* xs = (const float2*)&sm[OX + (2 * py + t) * 28 + cc0];
            float row[18];
            #pragma unroll
            for (int p = 0; p < 9; ++p) {
                float2 v = xs[p];
                row[2 * p] = v.x; row[2 * p + 1] = v.y;
            }
            if (t <= 6) {
                #pragma unroll
                for (int kx = 0; kx < 7; ++kx)
                    #pragma unroll
                    for (int cc = 0; cc < 12; ++cc)
                        c[0][cc] = fmaf(wc[kx], row[cc + kx], c[0][cc]);
            }
            if (t >= 1) {
                #pragma unroll
                for (int kx = 0; kx < 7; ++kx)
                    #pragma unroll
                    for (int cc = 0; cc < 12; ++cc)
                        c[1][cc] = fmaf(wp[kx], row[cc + kx], c[1][cc]);
            }
            #pragma unroll
            for (int i = 0; i < 7; ++i) wp[i] = wc[i];
            if (t < 7) {
                const float* wn = wg + (t + 1) * 7;
                #pragma unroll
                for (int i = 0; i < 7; ++i) wc[i] = wn[i];
            }
        }
        float b = kf_b1[oc];
        #pragma unroll
        for (int j = 0; j < 6; ++j) {
            if (h == 0 || j < 5) {
                float m = fmaxf(fmaxf(c[0][2 * j], c[0][2 * j + 1]),
                                fmaxf(c[1][2 * j], c[1][2 * j + 1]));
                sm[OC1 + oc * 132 + py * 12 + 6 * h + j] = fmaxf(m + b, 0.f);
            }
        }
    }
    __syncthreads();

    // ---- conv5 (11->7 used 6x6) + pool (->3) + relu, full-depth ----
    // oc = tid%10 broadcast; rows via 3x b64 (even offsets on stride-12 c1).
    if (tid < 90) {
        int oc = tid % 10, r = tid / 10;
        int py = r / 3, px = r % 3;
        float a00 = 0.f, a01 = 0.f, a10 = 0.f, a11 = 0.f;
        for (int ic = 0; ic < 8; ++ic) {
            float w[25];
            const float* wg = kf_w2 + (oc * 8 + ic) * 25;
            #pragma unroll
            for (int i = 0; i < 25; ++i) w[i] = wg[i];
            const float* xb = &sm[OC1 + ic * 132 + (2 * py) * 12 + 2 * px];
            float cur[6], nxt[6];
            #pragma unroll
            for (int p = 0; p < 3; ++p) {
                float2 v = ((const float2*)xb)[p];
                cur[2 * p] = v.x; cur[2 * p + 1] = v.y;
            }
            #pragma unroll
            for (int ky = 0; ky < 5; ++ky) {
                const float2* xr = (const float2*)(xb + (ky + 1) * 12);
                #pragma unroll
                for (int p = 0; p < 3; ++p) {
                    float2 v = xr[p];
                    nxt[2 * p] = v.x; nxt[2 * p + 1] = v.y;
                }
                #pragma unroll
                for (int kx = 0; kx < 5; ++kx) {
                    float wv = w[ky * 5 + kx];
                    a00 = fmaf(wv, cur[kx],     a00);
                    a01 = fmaf(wv, cur[kx + 1], a01);
                    a10 = fmaf(wv, nxt[kx],     a10);
                    a11 = fmaf(wv, nxt[kx + 1], a11);
                }
                #pragma unroll
                for (int i = 0; i < 6; ++i) cur[i] = nxt[i];
            }
        }
        float m = fmaxf(fmaxf(a00, a01), fmaxf(a10, a11)) + kf_b2[oc];
        sm[OF + oc * 9 + py * 3 + px] = fmaxf(m, 0.f);
    }
    __syncthreads();

    // ---- fc 90->32 + relu, then fc 32->40: both wave 0, no barrier between ----
    if (tid < 32) {
        float acc = kf_fc1_b[tid];
        const float* wr = &kf_fc1_w[tid * 90];
        for (int i = 0; i < 90; ++i) acc = fmaf(wr[i], sm[OF + i], acc);
        sm[OH + tid] = fmaxf(acc, 0.f);
    }
    if (tid < 40) {
        float acc = kf_fc2_b[tid];
        const float* wr = &kf_fc2_w[tid * 32];
        #pragma unroll
        for (int i = 0; i < 32; ++i) acc = fmaf(wr[i], sm[OH + i], acc);
        sm[OK2 + tid] = acc;
    }
    __syncthreads();

    // ---- dynamic 2x2 conv + pool + relu -> y [10][13][20]; b64 x reads ----
    if (tid < 130) {
        int oc = tid % 10, py = tid / 10;
        float k0 = sm[OK2 + oc * 4 + 0], k1 = sm[OK2 + oc * 4 + 1];
        float k2 = sm[OK2 + oc * 4 + 2], k3 = sm[OK2 + oc * 4 + 3];
        const float2* x0 = (const float2*)&sm[OX + 2 * py * 28];
        const float2* x1 = x0 + 14;
        const float2* x2 = x0 + 28;
        float2 i0 = x0[0], i1 = x1[0], i2 = x2[0];
        float A0 = i0.x, B0 = i0.y;
        float A1 = i1.x, B1 = i1.y;
        float A2 = i2.x, B2 = i2.y;
        #pragma unroll
        for (int j = 0; j < 13; ++j) {
            float2 n0 = x0[j + 1], n1 = x1[j + 1], n2 = x2[j + 1];
            float c00 = A0 * k0 + B0 * k1 + A1 * k2 + B1 * k3;
            float c01 = B0 * k0 + n0.x * k1 + B1 * k2 + n1.x * k3;
            float c10 = A1 * k0 + B1 * k1 + A2 * k2 + B2 * k3;
            float c11 = B1 * k0 + n1.x * k1 + B2 * k2 + n2.x * k3;
            float m = fmaxf(fmaxf(c00, c01), fmaxf(c10, c11));
            sm[OY + oc * 260 + py * 20 + j] = fmaxf(m, 0.f);
            A0 = n0.x; B0 = n0.y;
            A1 = n1.x; B1 = n1.y;
            A2 = n2.x; B2 = n2.y;
        }
    }
    __syncthreads();

    // ---- conv2 5x5 (8x8 used): (h2, rg4, oc20); rows via 3x b128 on stride-20 y
    // (start banks disjoint per wave: {s,s+8,s+20} / {s+4,s+16,s+28} / {s+12,s+24}).
    if (tid < 160) {
        int oc = tid % 20, q = tid / 20;
        int h = q & 1, rg = q >> 1;
        int r0 = 2 * rg;
        float acc[2][8];
        #pragma unroll
        for (int r = 0; r < 2; ++r)
            #pragma unroll
            for (int i = 0; i < 8; ++i) acc[r][i] = 0.f;
        for (int icg = 0; icg < 5; ++icg) {
            int ic = 5 * h + icg;
            float w[25];
            const float* wg = conv2_w + (oc * 10 + ic) * 25;
            #pragma unroll
            for (int i = 0; i < 25; ++i) w[i] = wg[i];
            const float* yb = &sm[OY + ic * 260 + r0 * 20];
            #pragma unroll
            for (int u = 0; u < 6; ++u) {
                const float4* ys = (const float4*)(yb + u * 20);
                float4 q0 = ys[0], q1 = ys[1], q2 = ys[2];
                float row[12] = {q0.x,q0.y,q0.z,q0.w, q1.x,q1.y,q1.z,q1.w,
                                 q2.x,q2.y,q2.z,q2.w};
                #pragma unroll
                for (int rr = 0; rr < 2; ++rr) {
                    int ky = u - rr;
                    if (ky >= 0 && ky <= 4) {
                        #pragma unroll
                        for (int kx = 0; kx < 5; ++kx)
                            #pragma unroll
                            for (int cx = 0; cx < 8; ++cx)
                                acc[rr][cx] = fmaf(w[ky * 5 + kx], row[cx + kx], acc[rr][cx]);
                    }
                }
            }
        }
        #pragma unroll
        for (int rr = 0; rr < 2; ++rr)
            #pragma unroll
            for (int cx = 0; cx < 8; ++cx)
                sm[OP2 + h * 1300 + oc * 65 + (r0 + rr) * 8 + cx] = acc[rr][cx];
    }
    __syncthreads();

    // ---- fused combine(ic-halves)+bias+pool+relu -> p3[20,4,4] ----
    for (int idx = tid; idx < 320; idx += TPB) {
        int oc = idx / 16, rem = idx % 16;
        int py = rem / 4, px = rem % 4;
        int base = oc * 65 + (2 * py) * 8 + 2 * px;
        float b = conv2_b[oc];
        const float* p0 = &sm[OP2 + base];
        const float* p1 = &sm[OP2 + 1300 + base];
        float c00 = b + p0[0] + p1[0];
        float c01 = b + p0[1] + p1[1];
        float c10 = b + p0[8] + p1[8];
        float c11 = b + p0[9] + p1[9];
        float m = fmaxf(fmaxf(c00, c01), fmaxf(c10, c11));
        sm[OP3 + idx] = fmaxf(m, 0.f);
    }
    __syncthreads();

    // ---- fc 320->50, 5-way k-split (scalar LDS: b128 here would 5-way
    // conflict at bank 0 since all g-chunks start 64-aligned) ----
    if (tid < 250) {
        int g = tid / 50, o = tid % 50;
        const float* wr = &fc1_w[o * 320 + g * 64];
        const float* pp = &sm[OP3 + g * 64];
        float acc = 0.f;
        #pragma unroll
        for (int i = 0; i < 64; ++i) acc = fmaf(wr[i], pp[i], acc);
        sm[OPF + tid] = acc;
    }
    __syncthreads();

    // ---- tail: all wave 0, barrier-free ----
    if (tid < 50) {
        float a = fc1_b[tid];
        #pragma unroll
        for (int g = 0; g < 5; ++g) a += sm[OPF + g * 50 + tid];
        sm[OA1 + tid] = fmaxf(a, 0.f);
    }
    if (tid < 10) {
        float a = fc2_b[tid];
        const float* wr = &fc2_w[tid * 50];
        #pragma unroll
        for (int i = 0; i < 50; ++i) a = fmaf(wr[i], sm[OA1 + i], a);
        sm[OZ + tid] = a;
    }
    if (tid < 10) {
        float m = sm[OZ + 0];
        #pragma unroll
        for (int i = 1; i < 10; ++i) m = fmaxf(m, sm[OZ + i]);
        float s = 0.f;
        #pragma unroll
        for (int i = 0; i < 10; ++i) s += expf(sm[OZ + i] - m);
        out[n * 10 + tid] = sm[OZ + tid] - m - logf(s);
    }
}

extern "C" void kernel_launch(void* const* d_in, const int* in_sizes, int n_in,
                              void* d_out, int out_size, void* d_ws, size_t ws_size,
                              hipStream_t stream) {
    const float* x        = (const float*)d_in[0];
    const float* kf_w1    = (const float*)d_in[1];
    const float* kf_b1    = (const float*)d_in[2];
    const float* kf_w2    = (const float*)d_in[3];
    const float* kf_b2    = (const float*)d_in[4];
    const float* kf_fc1_w = (const float*)d_in[5];
    const float* kf_fc1_b = (const float*)d_in[6];
    const float* kf_fc2_w = (const float*)d_in[7];
    const float* kf_fc2_b = (const float*)d_in[8];
    const float* conv2_w  = (const float*)d_in[9];
    const float* conv2_b  = (const float*)d_in[10];
    const float* fc1_w    = (const float*)d_in[11];
    const float* fc1_b    = (const float*)d_in[12];
    const float* fc2_w    = (const float*)d_in[13];
    const float* fc2_b    = (const float*)d_in[14];

    const int N = in_sizes[0] / 784;   // 8192

    fused_forward<<<N, TPB, 0, stream>>>(
        x, kf_w1, kf_b1, kf_w2, kf_b2, kf_fc1_w, kf_fc1_b, kf_fc2_w, kf_fc2_b,
        conv2_w, conv2_b, fc1_w, fc1_b, fc2_w, fc2_b, (float*)d_out);
}

// Round 10
// 294.515 us; speedup vs baseline: 1.2869x; 1.2869x over previous
//
#include <hip/hip_runtime.h>
#include <math.h>

#define TPB 256

// ---- LDS layout (float offsets), lifetime-overlaid. Weights in GLOBAL/L2. ----
// x   [0,784)      flat [28][28]
// c1  [784,1840)   conv7 out [8][11] stride 12 (even -> b64 reads in conv5)
// y   [784,2604)   dyn out [10][13] stride 14 (even -> b64 reads in conv2)
// f   [2604,2694) h [2694,2726) k [2726,2766)   (dead before conv2)
// P2  [2604,5204)  conv2 partials [2][20][65] (over f/h/k after death)
// p3  [0,320) pf [320,570) a1 [570,620) z [620,630)  (x dead after dyn)
#define OX    0
#define OC1   784
#define OY    784
#define OF    2604
#define OH    2694
#define OK2   2726
#define OP2   2604
#define OP3   0
#define OPF   320
#define OA1   570
#define OZ    620
#define SM_TOT 5204   // 20816 B -> 7 blocks/CU

// VGPR discipline (R8: 84, R9: 88 — both halved the wave cap and regressed):
// conv7 + dyn stay SCALAR (their vector forms blew the live set). b64 only in
// conv5/conv2 whose live arrays are small and already existed in R7's 40-VGPR
// build. No min-waves launch bound (R3: forced low VGPR -> scratch spill).
__global__ __launch_bounds__(TPB) void fused_forward(
    const float* __restrict__ x,
    const float* __restrict__ kf_w1, const float* __restrict__ kf_b1,
    const float* __restrict__ kf_w2, const float* __restrict__ kf_b2,
    const float* __restrict__ kf_fc1_w, const float* __restrict__ kf_fc1_b,
    const float* __restrict__ kf_fc2_w, const float* __restrict__ kf_fc2_b,
    const float* __restrict__ conv2_w, const float* __restrict__ conv2_b,
    const float* __restrict__ fc1_w, const float* __restrict__ fc1_b,
    const float* __restrict__ fc2_w, const float* __restrict__ fc2_b,
    float* __restrict__ out)
{
    __shared__ float sm[SM_TOT];
    const int tid = threadIdx.x;
    const int n = blockIdx.x;

    // ---- stage 0: stage x into LDS (float4 flat copy) ----
    {
        const float4* xg = (const float4*)(x + (long long)n * 784);
        float4* d = (float4*)&sm[OX];
        for (int i = tid; i < 196; i += TPB) d[i] = xg[i];
    }
    __syncthreads();

    // ---- conv7 (28->22) + pool (->11) + relu — SCALAR reads (R7 form) ----
    // oc = tid&7 broadcast; h0 -> pooled px 0..5, h1 -> px 6..10.
    if (tid < 176) {
        int oc = tid & 7;
        int r  = tid >> 3;
        int py = r >> 1;
        int h  = r & 1;
        int cc0 = 10 * h;
        float c[2][12];
        #pragma unroll
        for (int r2 = 0; r2 < 2; ++r2)
            #pragma unroll
            for (int i = 0; i < 12; ++i) c[r2][i] = 0.f;
        float wc[7], wp[7];
        const float* wg = kf_w1 + oc * 49;
        #pragma unroll
        for (int i = 0; i < 7; ++i) wc[i] = wg[i];
        #pragma unroll
        for (int t = 0; t < 8; ++t) {
            const float* xs = &sm[OX + (2 * py + t) * 28 + cc0];
            float row[18];
            #pragma unroll
            for (int i = 0; i < 18; ++i) row[i] = xs[i];
            if (t <= 6) {
                #pragma unroll
                for (int kx = 0; kx < 7; ++kx)
                    #pragma unroll
                    for (int cc = 0; cc < 12; ++cc)
                        c[0][cc] = fmaf(wc[kx], row[cc + kx], c[0][cc]);
            }
            if (t >= 1) {
                #pragma unroll
                for (int kx = 0; kx < 7; ++kx)
                    #pragma unroll
                    for (int cc = 0; cc < 12; ++cc)
                        c[1][cc] = fmaf(wp[kx], row[cc + kx], c[1][cc]);
            }
            #pragma unroll
            for (int i = 0; i < 7; ++i) wp[i] = wc[i];
            if (t < 7) {
                const float* wn = wg + (t + 1) * 7;
                #pragma unroll
                for (int i = 0; i < 7; ++i) wc[i] = wn[i];
            }
        }
        float b = kf_b1[oc];
        #pragma unroll
        for (int j = 0; j < 6; ++j) {
            float m = fmaxf(fmaxf(c[0][2 * j], c[0][2 * j + 1]),
                            fmaxf(c[1][2 * j], c[1][2 * j + 1]));
            sm[OC1 + oc * 132 + py * 12 + 5 * h + j] = fmaxf(m + b, 0.f);
        }
    }
    __syncthreads();

    // ---- conv5 (11->7 used 6x6) + pool (->3) + relu, full-depth, b64 reads ----
    // oc = tid%10 broadcast; c1 stride 12: all row reads are 3x float2 at even
    // addrs; lane start banks {0,2,4,24,26,28,16,18,20} disjoint.
    if (tid < 90) {
        int oc = tid % 10, r = tid / 10;
        int py = r / 3, px = r % 3;
        float a00 = 0.f, a01 = 0.f, a10 = 0.f, a11 = 0.f;
        for (int ic = 0; ic < 8; ++ic) {
            float w[25];
            const float* wg = kf_w2 + (oc * 8 + ic) * 25;
            #pragma unroll
            for (int i = 0; i < 25; ++i) w[i] = wg[i];
            const float* xb = &sm[OC1 + ic * 132 + (2 * py) * 12 + 2 * px];
            float cur[6], nxt[6];
            #pragma unroll
            for (int p = 0; p < 3; ++p) {
                float2 v = ((const float2*)xb)[p];
                cur[2 * p] = v.x; cur[2 * p + 1] = v.y;
            }
            #pragma unroll
            for (int ky = 0; ky < 5; ++ky) {
                const float2* xr = (const float2*)(xb + (ky + 1) * 12);
                #pragma unroll
                for (int p = 0; p < 3; ++p) {
                    float2 v = xr[p];
                    nxt[2 * p] = v.x; nxt[2 * p + 1] = v.y;
                }
                #pragma unroll
                for (int kx = 0; kx < 5; ++kx) {
                    float wv = w[ky * 5 + kx];
                    a00 = fmaf(wv, cur[kx],     a00);
                    a01 = fmaf(wv, cur[kx + 1], a01);
                    a10 = fmaf(wv, nxt[kx],     a10);
                    a11 = fmaf(wv, nxt[kx + 1], a11);
                }
                #pragma unroll
                for (int i = 0; i < 6; ++i) cur[i] = nxt[i];
            }
        }
        float m = fmaxf(fmaxf(a00, a01), fmaxf(a10, a11)) + kf_b2[oc];
        sm[OF + oc * 9 + py * 3 + px] = fmaxf(m, 0.f);
    }
    __syncthreads();

    // ---- fc 90->32 + relu, then fc 32->40: both wave 0, no barrier between ----
    if (tid < 32) {
        float acc = kf_fc1_b[tid];
        const float* wr = &kf_fc1_w[tid * 90];
        for (int i = 0; i < 90; ++i) acc = fmaf(wr[i], sm[OF + i], acc);
        sm[OH + tid] = fmaxf(acc, 0.f);
    }
    if (tid < 40) {
        float acc = kf_fc2_b[tid];
        const float* wr = &kf_fc2_w[tid * 32];
        #pragma unroll
        for (int i = 0; i < 32; ++i) acc = fmaf(wr[i], sm[OH + i], acc);
        sm[OK2 + tid] = acc;
    }
    __syncthreads();

    // ---- dynamic 2x2 conv + pool + relu -> y [10][13] stride 14 — SCALAR ----
    if (tid < 130) {
        int oc = tid % 10, py = tid / 10;
        float k0 = sm[OK2 + oc * 4 + 0], k1 = sm[OK2 + oc * 4 + 1];
        float k2 = sm[OK2 + oc * 4 + 2], k3 = sm[OK2 + oc * 4 + 3];
        const float* x0 = &sm[OX + 2 * py * 28];
        const float* x1 = x0 + 28;
        const float* x2 = x0 + 56;
        float A0 = x0[0], A1 = x1[0], A2 = x2[0];
        float B0 = x0[1], B1 = x1[1], B2 = x2[1];
        #pragma unroll
        for (int j = 0; j < 13; ++j) {
            float C0 = x0[2 * j + 2], C1 = x1[2 * j + 2], C2 = x2[2 * j + 2];
            float c00 = A0 * k0 + B0 * k1 + A1 * k2 + B1 * k3;
            float c01 = B0 * k0 + C0 * k1 + B1 * k2 + C1 * k3;
            float c10 = A1 * k0 + B1 * k1 + A2 * k2 + B2 * k3;
            float c11 = B1 * k0 + C1 * k1 + B2 * k2 + C2 * k3;
            float m = fmaxf(fmaxf(c00, c01), fmaxf(c10, c11));
            sm[OY + oc * 182 + py * 14 + j] = fmaxf(m, 0.f);
            A0 = C0; A1 = C1; A2 = C2;
            if (j < 12) { B0 = x0[2 * j + 3]; B1 = x1[2 * j + 3]; B2 = x2[2 * j + 3]; }
        }
    }
    __syncthreads();

    // ---- conv2 5x5 (8x8 used): (h2, rg4, oc20); b64 reads on stride-14 y ----
    // row of 12 = 6x float2 at even addrs; 4 addr streams/wave, banks spread.
    if (tid < 160) {
        int oc = tid % 20, q = tid / 20;
        int h = q & 1, rg = q >> 1;
        int r0 = 2 * rg;
        float acc[2][8];
        #pragma unroll
        for (int r = 0; r < 2; ++r)
            #pragma unroll
            for (int i = 0; i < 8; ++i) acc[r][i] = 0.f;
        for (int icg = 0; icg < 5; ++icg) {
            int ic = 5 * h + icg;
            float w[25];
            const float* wg = conv2_w + (oc * 10 + ic) * 25;
            #pragma unroll
            for (int i = 0; i < 25; ++i) w[i] = wg[i];
            const float* yb = &sm[OY + ic * 182 + r0 * 14];
            #pragma unroll
            for (int u = 0; u < 6; ++u) {
                const float2* ys = (const float2*)(yb + u * 14);
                float row[12];
                #pragma unroll
                for (int p = 0; p < 6; ++p) {
                    float2 v = ys[p];
                    row[2 * p] = v.x; row[2 * p + 1] = v.y;
                }
                #pragma unroll
                for (int rr = 0; rr < 2; ++rr) {
                    int ky = u - rr;
                    if (ky >= 0 && ky <= 4) {
                        #pragma unroll
                        for (int kx = 0; kx < 5; ++kx)
                            #pragma unroll
                            for (int cx = 0; cx < 8; ++cx)
                                acc[rr][cx] = fmaf(w[ky * 5 + kx], row[cx + kx], acc[rr][cx]);
                    }
                }
            }
        }
        #pragma unroll
        for (int rr = 0; rr < 2; ++rr)
            #pragma unroll
            for (int cx = 0; cx < 8; ++cx)
                sm[OP2 + h * 1300 + oc * 65 + (r0 + rr) * 8 + cx] = acc[rr][cx];
    }
    __syncthreads();

    // ---- fused combine(ic-halves)+bias+pool+relu -> p3[20,4,4] ----
    for (int idx = tid; idx < 320; idx += TPB) {
        int oc = idx / 16, rem = idx % 16;
        int py = rem / 4, px = rem % 4;
        int base = oc * 65 + (2 * py) * 8 + 2 * px;
        float b = conv2_b[oc];
        const float* p0 = &sm[OP2 + base];
        const float* p1 = &sm[OP2 + 1300 + base];
        float c00 = b + p0[0] + p1[0];
        float c01 = b + p0[1] + p1[1];
        float c10 = b + p0[8] + p1[8];
        float c11 = b + p0[9] + p1[9];
        float m = fmaxf(fmaxf(c00, c01), fmaxf(c10, c11));
        sm[OP3 + idx] = fmaxf(m, 0.f);
    }
    __syncthreads();

    // ---- fc 320->50, 5-way k-split (scalar LDS reads) ----
    if (tid < 250) {
        int g = tid / 50, o = tid % 50;
        const float* wr = &fc1_w[o * 320 + g * 64];
        const float* pp = &sm[OP3 + g * 64];
        float acc = 0.f;
        #pragma unroll
        for (int i = 0; i < 64; ++i) acc = fmaf(wr[i], pp[i], acc);
        sm[OPF + tid] = acc;
    }
    __syncthreads();

    // ---- tail: all wave 0, barrier-free ----
    if (tid < 50) {
        float a = fc1_b[tid];
        #pragma unroll
        for (int g = 0; g < 5; ++g) a += sm[OPF + g * 50 + tid];
        sm[OA1 + tid] = fmaxf(a, 0.f);
    }
    if (tid < 10) {
        float a = fc2_b[tid];
        const float* wr = &fc2_w[tid * 50];
        #pragma unroll
        for (int i = 0; i < 50; ++i) a = fmaf(wr[i], sm[OA1 + i], a);
        sm[OZ + tid] = a;
    }
    if (tid < 10) {
        float m = sm[OZ + 0];
        #pragma unroll
        for (int i = 1; i < 10; ++i) m = fmaxf(m, sm[OZ + i]);
        float s = 0.f;
        #pragma unroll
        for (int i = 0; i < 10; ++i) s += expf(sm[OZ + i] - m);
        out[n * 10 + tid] = sm[OZ + tid] - m - logf(s);
    }
}

extern "C" void kernel_launch(void* const* d_in, const int* in_sizes, int n_in,
                              void* d_out, int out_size, void* d_ws, size_t ws_size,
                              hipStream_t stream) {
    const float* x        = (const float*)d_in[0];
    const float* kf_w1    = (const float*)d_in[1];
    const float* kf_b1    = (const float*)d_in[2];
    const float* kf_w2    = (const float*)d_in[3];
    const float* kf_b2    = (const float*)d_in[4];
    const float* kf_fc1_w = (const float*)d_in[5];
    const float* kf_fc1_b = (const float*)d_in[6];
    const float* kf_fc2_w = (const float*)d_in[7];
    const float* kf_fc2_b = (const float*)d_in[8];
    const float* conv2_w  = (const float*)d_in[9];
    const float* conv2_b  = (const float*)d_in[10];
    const float* fc1_w    = (const float*)d_in[11];
    const float* fc1_b    = (const float*)d_in[12];
    const float* fc2_w    = (const float*)d_in[13];
    const float* fc2_b    = (const float*)d_in[14];

    const int N = in_sizes[0] / 784;   // 8192

    fused_forward<<<N, TPB, 0, stream>>>(
        x, kf_w1, kf_b1, kf_w2, kf_b2, kf_fc1_w, kf_fc1_b, kf_fc2_w, kf_fc2_b,
        conv2_w, conv2_b, fc1_w, fc1_b, fc2_w, fc2_b, (float*)d_out);
}